// Round 5
// baseline (186.461 us; speedup 1.0000x reference)
//
#include <hip/hip_runtime.h>
#include <hip/hip_bf16.h>

// B,C,H,W = 4,64,64,64 ; N = 4096 ; d = 8
#define BB 4
#define CC 64
#define NN 4096

typedef __attribute__((ext_vector_type(8))) short short8;
typedef __attribute__((ext_vector_type(4))) float f32x4;

__device__ inline ushort f2bf(float x) {                 // RNE float->bf16
    unsigned u = __float_as_uint(x);
    return (ushort)((u + 0x7fff + ((u >> 16) & 1)) >> 16);
}
__device__ inline float bf2f(ushort h) { return __uint_as_float(((unsigned)h) << 16); }

// ws layout (ushort):
//   qTp [B][N][32] : q0..q7, q0h,q1h,q0l,q1l, 0*20               (1 MB)
//   kTp [B][N][32] : k0..k7, col,row,col,row, 0*20               (1 MB)
//   vsw [B][64t][2s*4g][64 lane][8 jj]  B-frag swizzled bf16 V   (2 MB)
//   kmax [B][8] fp32-as-uint (atomicMax of |bf16 k_d|), memset 0 first

// ---------------------------------------------------------------------------
// Kernel 1: QKV projection. Grid 512 x 256 threads.
// Blocks 0..255  (v path): (b, t4, eblk) -> 16 BLOCK-UNIFORM v-rows x 256 px.
//   Weight rows derived from blockIdx => compiler emits scalar s_loads (the
//   R2 structure that ran ~30us; R4's tid-derived rows forced vector loads).
//   bf16 results -> LDS [row][px pad 264] -> ds_read_b128 repack -> coalesced
//   uint4 stores into the vsw B-frag swizzle.
// Blocks 256..511 (qk path): (b, t) -> 64 px, 4 threads/px split c 4-ways,
//   shfl_xor reduce (all lanes get full sums), records built in-register.
// ---------------------------------------------------------------------------
__global__ __launch_bounds__(256) void qkv_kernel(
    const float* __restrict__ x,
    const float* __restrict__ Wq, const float* __restrict__ bq,
    const float* __restrict__ Wk, const float* __restrict__ bk,
    const float* __restrict__ Wv, const float* __restrict__ bv,
    ushort* __restrict__ qTp, ushort* __restrict__ kTp,
    ushort* __restrict__ vsw, unsigned* __restrict__ kmax)
{
    const int blk = blockIdx.x, tid = threadIdx.x;

    if (blk >= 256) {
        // ---------------- qk path ----------------
        const int b = (blk - 256) >> 6, t = (blk - 256) & 63;
        const int px = tid >> 2, cp = tid & 3;
        const int n = t * 64 + px;

        const float* xb = x + (size_t)(b * CC) * NN + n;
        float xc[16];
#pragma unroll
        for (int u = 0; u < 16; ++u) xc[u] = xb[(size_t)(cp * 16 + u) * NN];

        float s[16];
#pragma unroll
        for (int r = 0; r < 16; ++r) {
            const float* wr = (r < 8) ? (Wq + r * CC) : (Wk + (r - 8) * CC);  // block... r-uniform rows
            float a = 0.f;
#pragma unroll
            for (int u = 0; u < 16; ++u) a += wr[cp * 16 + u] * xc[u];
            s[r] = a;
        }
#pragma unroll
        for (int r = 0; r < 16; ++r) {
            s[r] += __shfl_xor(s[r], 1, 64);
            s[r] += __shfl_xor(s[r], 2, 64);          // all 4 lanes now hold full sum
            s[r] += (r < 8) ? bq[r] : bk[r - 8];
        }

        // per-batch |k_d| max (bf16-rounded values actually used)
#pragma unroll
        for (int d = 0; d < 8; ++d) {
            float kv = fabsf(bf2f(f2bf(s[8 + d])));
#pragma unroll
            for (int off = 1; off < 64; off <<= 1) kv = fmaxf(kv, __shfl_xor(kv, off, 64));
            if ((tid & 63) == 0) atomicMax(kmax + b * 8 + d, __float_as_uint(kv));
        }

        // build records (all lanes have data; store split across cp for balance)
        ushort hq[16], hk[16];
#pragma unroll
        for (int d = 0; d < 8; ++d) { hq[d] = f2bf(s[d]); hk[d] = f2bf(s[8 + d]); }
        hq[8]  = hq[0];  hq[9]  = hq[1];
        hq[10] = f2bf(s[0] - bf2f(hq[0]));
        hq[11] = f2bf(s[1] - bf2f(hq[1]));
        const ushort hc = f2bf((float)px), hr = f2bf((float)t);
        hk[8] = hc; hk[9] = hr; hk[10] = hc; hk[11] = hr;
#pragma unroll
        for (int i = 12; i < 16; ++i) { hq[i] = 0; hk[i] = 0; }

        const uint4 z = {0u, 0u, 0u, 0u};
        uint4* dq = (uint4*)(qTp + (size_t)(b * NN + n) * 32);
        uint4* dk = (uint4*)(kTp + (size_t)(b * NN + n) * 32);
        if (cp == 0) { dq[0] = ((const uint4*)hq)[0]; dq[1] = ((const uint4*)hq)[1]; }
        if (cp == 1) { dq[2] = z; dq[3] = z; }
        if (cp == 2) { dk[0] = ((const uint4*)hk)[0]; dk[1] = ((const uint4*)hk)[1]; }
        if (cp == 3) { dk[2] = z; dk[3] = z; }
        return;
    }

    // ---------------- v path ----------------
    const int b = blk >> 6, t4 = (blk & 63) >> 2, eblk = blk & 3;
    const int px = tid;                      // 0..255
    const int n = t4 * 256 + px;

    __shared__ ushort vls[16 * 264];         // [row][px], stride 264 halves

    const float* xb = x + (size_t)(b * CC) * NN + n;
    float xc[CC];
#pragma unroll
    for (int c = 0; c < CC; ++c) xc[c] = xb[(size_t)c * NN];

#pragma unroll
    for (int r = 0; r < 16; ++r) {
        const int e = eblk * 16 + r;         // block-uniform row -> scalar weight loads
        const float* wr = Wv + e * CC;
        float a = bv[e];
#pragma unroll
        for (int c = 0; c < CC; ++c) a += wr[c] * xc[c];
        vls[r * 264 + px] = f2bf(a);
    }
    __syncthreads();

    // repack: chunk cidx -> (tt,s,quad,nn); 8 px-consecutive bf16 = 1 b128 read
#pragma unroll
    for (int i = 0; i < 2; ++i) {
        const int cidx = tid + i * 256;
        const int nn = cidx & 15, quad = (cidx >> 4) & 3, s = (cidx >> 6) & 1, tt = cidx >> 7;
        const uint4 v4 = *(const uint4*)(vls + nn * 264 + tt * 64 + s * 32 + quad * 8);
        *(uint4*)(vsw + ((size_t)(b * 64 + t4 * 4 + tt) * 512 + (s * 4 + eblk) * 64 + quad * 16 + nn) * 8) = v4;
    }
}

// ---------------------------------------------------------------------------
// Kernel 2: single-pass MFMA attention, register-resident P via ds_bpermute.
// 512 blocks = (b, 32-query tile), 512 threads = 8 waves, 8-way key split.
// C-layout->A-layout exchange: A-dword m of lane(nn,q), kstep s, equals
// C-dword (m&1) of chunk kg=2s+(q>>1) from lane ((q&1)*2+(m>>1))*16+nn.
// Two bpermutes (kg, kg+1) + cndmask on q>>1. No P LDS, no bank conflicts.
// ---------------------------------------------------------------------------
__global__ __launch_bounds__(512, 4) void attn_kernel(
    const ushort* __restrict__ qTp, const ushort* __restrict__ kTp,
    const ushort* __restrict__ vsw, const unsigned* __restrict__ kmaxu,
    float* __restrict__ out)
{
    const int blk = blockIdx.x;
    const int b = blk >> 7, nq = (blk & 127) * 32;
    const int tid = threadIdx.x, wv = tid >> 6, lane = tid & 63;
    const int nn = lane & 15, quad = lane >> 4;

    __shared__ float obuf[32 * 81];      // [q][81]: ch 0..63 = out, 64 = den
    for (int i = tid; i < 32 * 81; i += 512) obuf[i] = 0.f;

    // Q B-frags: lane holds channels quad*8..+8 of query (nq + qg*16 + nn)
    short8 qf[2];
    qf[0] = *(const short8*)(qTp + (size_t)(b * NN + nq + nn) * 32 + quad * 8);
    qf[1] = *(const short8*)(qTp + (size_t)(b * NN + nq + 16 + nn) * 32 + quad * 8);

    // ---- safe per-query softmax shift M~ (overestimate cancels in softmax) ----
    float Mq[2];
    {
        const float* kmax = (const float*)kmaxu + b * 8;
#pragma unroll
        for (int qg = 0; qg < 2; ++qg) {
            float B1 = 0.f;   // valid on quad 0 (channels 0..7)
#pragma unroll
            for (int d = 0; d < 8; ++d) B1 += fabsf(bf2f((ushort)qf[qg][d])) * kmax[d];
            // valid on quad 1 (channels 8..11 = q0h,q1h,q0l,q1l)
            const float q0 = bf2f((ushort)qf[qg][0]) + bf2f((ushort)qf[qg][2]);
            const float q1 = bf2f((ushort)qf[qg][1]) + bf2f((ushort)qf[qg][3]);
            const float rel = fmaxf(q0 * 63.f, 0.f) + fmaxf(q1 * 63.f, 0.f);
            const float z  = (quad == 0) ? B1 : ((quad == 1) ? rel : 0.f);
            const float r1 = __shfl_xor(z, 16, 64);
            const float myB1  = (quad == 0) ? z : r1;
            const float myRel = (quad == 0) ? r1 : z;
            float f = myRel + fmaxf(myB1 - 20.f, 0.f) + 1.f;
            f = (quad < 2) ? f : 0.f;
            Mq[qg] = f + __shfl_xor(f, 32, 64);
        }
    }

    f32x4 acc[2][4];
#pragma unroll
    for (int qg = 0; qg < 2; ++qg)
#pragma unroll
        for (int g = 0; g < 4; ++g) acc[qg][g] = (f32x4){0.f, 0.f, 0.f, 0.f};
    float den[2] = {0.f, 0.f};

    const ushort* kb  = kTp + (size_t)b * NN * 32;
    const ushort* vb0 = vsw + (size_t)b * 64 * 512 * 8;
    const int addr0 = (((quad & 1) * 2 + 0) * 16 + nn) * 4;   // bpermute src (h=0)
    const int addr1 = (((quad & 1) * 2 + 1) * 16 + nn) * 4;   // bpermute src (h=1)
    const int hi = quad >> 1;                                  // kg select

    __syncthreads();   // obuf zeros visible before post-loop ds_add

    for (int it = 0; it < 8; ++it) {
        const int t = wv + it * 8;
        short8 kf[4];
#pragma unroll
        for (int kg = 0; kg < 4; ++kg)
            kf[kg] = *(const short8*)(kb + (size_t)(t * 64 + kg * 16 + nn) * 32 + quad * 8);

        uint2 pk[2][4];
#pragma unroll
        for (int qg = 0; qg < 2; ++qg) {
#pragma unroll
            for (int kg = 0; kg < 4; ++kg) {
                f32x4 S = __builtin_amdgcn_mfma_f32_16x16x32_bf16(
                    kf[kg], qf[qg], (f32x4){0.f, 0.f, 0.f, 0.f}, 0, 0, 0);
                // lane = query nn ; regs = keys kg*16 + quad*4 .. +3
                const float w0 = __expf(S[0] - Mq[qg]);
                const float w1 = __expf(S[1] - Mq[qg]);
                const float w2 = __expf(S[2] - Mq[qg]);
                const float w3 = __expf(S[3] - Mq[qg]);
                union { __hip_bfloat162 h; unsigned u; } pa, pb;
                pa.h = __float22bfloat162_rn(make_float2(w0, w1));
                pb.h = __float22bfloat162_rn(make_float2(w2, w3));
                // denominator from the bf16-rounded weights (num/den consistent)
                den[qg] += __uint_as_float(pa.u << 16) + __uint_as_float(pa.u & 0xffff0000u)
                         + __uint_as_float(pb.u << 16) + __uint_as_float(pb.u & 0xffff0000u);
                pk[qg][kg].x = pa.u; pk[qg][kg].y = pb.u;
            }
        }

        // PV: A-frags via bpermute exchange, B = swizzled V' (global, L2-hot)
        const ushort* vt0 = vb0 + (size_t)t * 512 * 8;
#pragma unroll
        for (int s = 0; s < 2; ++s) {
            short8 vf[4];
#pragma unroll
            for (int g = 0; g < 4; ++g)
                vf[g] = *(const short8*)(vt0 + (size_t)((s * 4 + g) * 64 + lane) * 8);
#pragma unroll
            for (int qg = 0; qg < 2; ++qg) {
                const uint2 pkA = pk[qg][2 * s], pkB = pk[qg][2 * s + 1];
                union { uint4 u; short8 h; } af;
                {
                    const int r0 = __builtin_amdgcn_ds_bpermute(addr0, (int)pkA.x);
                    const int r1 = __builtin_amdgcn_ds_bpermute(addr0, (int)pkB.x);
                    af.u.x = (unsigned)(hi ? r1 : r0);
                }
                {
                    const int r0 = __builtin_amdgcn_ds_bpermute(addr0, (int)pkA.y);
                    const int r1 = __builtin_amdgcn_ds_bpermute(addr0, (int)pkB.y);
                    af.u.y = (unsigned)(hi ? r1 : r0);
                }
                {
                    const int r0 = __builtin_amdgcn_ds_bpermute(addr1, (int)pkA.x);
                    const int r1 = __builtin_amdgcn_ds_bpermute(addr1, (int)pkB.x);
                    af.u.z = (unsigned)(hi ? r1 : r0);
                }
                {
                    const int r0 = __builtin_amdgcn_ds_bpermute(addr1, (int)pkA.y);
                    const int r1 = __builtin_amdgcn_ds_bpermute(addr1, (int)pkB.y);
                    af.u.w = (unsigned)(hi ? r1 : r0);
                }
#pragma unroll
                for (int g = 0; g < 4; ++g)
                    acc[qg][g] = __builtin_amdgcn_mfma_f32_16x16x32_bf16(af.h, vf[g], acc[qg][g], 0, 0, 0);
            }
        }
    }

    // ---- combine across the 8 key-split waves ----
#pragma unroll
    for (int qg = 0; qg < 2; ++qg) {
        float d = den[qg];
        d += __shfl_xor(d, 16, 64);
        d += __shfl_xor(d, 32, 64);
        if (lane < 16) atomicAdd(&obuf[(qg * 16 + lane) * 81 + 64], d);
    }
#pragma unroll
    for (int qg = 0; qg < 2; ++qg)
#pragma unroll
        for (int g = 0; g < 4; ++g)
#pragma unroll
            for (int r = 0; r < 4; ++r)
                atomicAdd(&obuf[(qg * 16 + quad * 4 + r) * 81 + g * 16 + nn], acc[qg][g][r]);
    __syncthreads();

    // epilogue: out[b][c][nq+q] ; lanes 0..31 = consecutive n (coalesced)
    {
        const int q = tid & 31, c0 = tid >> 5;
#pragma unroll
        for (int i = 0; i < 4; ++i) {
            const int c = c0 + i * 16;
            out[(size_t)(b * CC + c) * NN + nq + q] = obuf[q * 81 + c] / obuf[q * 81 + 64];
        }
    }
}

extern "C" void kernel_launch(void* const* d_in, const int* in_sizes, int n_in,
                              void* d_out, int out_size, void* d_ws, size_t ws_size,
                              hipStream_t stream) {
    const float* x  = (const float*)d_in[0];
    const float* Wq = (const float*)d_in[1];
    const float* bq = (const float*)d_in[2];
    const float* Wk = (const float*)d_in[3];
    const float* bk = (const float*)d_in[4];
    const float* Wv = (const float*)d_in[5];
    const float* bv = (const float*)d_in[6];
    float* out = (float*)d_out;

    ushort* ws  = (ushort*)d_ws;
    ushort* qTp = ws;                                     // B*N*32 halves
    ushort* kTp = qTp + (size_t)BB * NN * 32;             // B*N*32 halves
    ushort* vsw = kTp + (size_t)BB * NN * 32;             // B*64*512*8 halves
    unsigned* kmax = (unsigned*)(vsw + (size_t)BB * 64 * 512 * 8);  // B*8

    hipMemsetAsync(kmax, 0, BB * 8 * sizeof(unsigned), stream);
    qkv_kernel<<<512, 256, 0, stream>>>(x, Wq, bq, Wk, bk, Wv, bv, qTp, kTp, vsw, kmax);
    attn_kernel<<<BB * 128, 512, 0, stream>>>(qTp, kTp, vsw, kmax, out);
}

// Round 6
// 159.563 us; speedup vs baseline: 1.1686x; 1.1686x over previous
//
#include <hip/hip_runtime.h>
#include <hip/hip_bf16.h>

// B,C,H,W = 4,64,64,64 ; N = 4096 ; d = 8
#define BB 4
#define CC 64
#define NN 4096

typedef __attribute__((ext_vector_type(8))) short short8;
typedef __attribute__((ext_vector_type(4))) float f32x4;

__device__ inline ushort f2bf(float x) {                 // RNE float->bf16
    unsigned u = __float_as_uint(x);
    return (ushort)((u + 0x7fff + ((u >> 16) & 1)) >> 16);
}
__device__ inline float bf2f(ushort h) { return __uint_as_float(((unsigned)h) << 16); }

// ws layout (ushort):
//   qTp [B][N][32] : q0..q7, q0h,q1h,q0l,q1l, 0*20               (1 MB)
//   kTp [B][N][32] : k0..k7, col,row,col,row, 0*20               (1 MB)
//   vsw [B][64t][2s*4g][64 lane][8 jj]  B-frag swizzled bf16 V   (2 MB)
//   kmax [B][8] fp32-bits as SIGNED int, atomicMax; 0xAA poison is a
//   negative int so no memset needed (positive-float bits are int-monotone).

// ---------------------------------------------------------------------------
// Kernel 1: QKV projection, R2-fast structure. 320 blocks x 256 threads.
// Blocks 0..255  (v path): (b, t4, eblk) -> 16 BLOCK-UNIFORM v-rows x 256 px
//   (scalar s_load weights), bf16 -> LDS [row][px pad 264] -> coalesced uint4
//   stores into the vsw B-frag swizzle.
// Blocks 256..319 (qk path): per-thread xv[64] + 16 unrolled block-uniform
//   dots (q0..7, k0..7), records built in-register, 4+4 uint4 stores.
// ---------------------------------------------------------------------------
__global__ __launch_bounds__(256) void qkv_kernel(
    const float* __restrict__ x,
    const float* __restrict__ Wq, const float* __restrict__ bq,
    const float* __restrict__ Wk, const float* __restrict__ bk,
    const float* __restrict__ Wv, const float* __restrict__ bv,
    ushort* __restrict__ qTp, ushort* __restrict__ kTp,
    ushort* __restrict__ vsw, int* __restrict__ kmax)
{
    const int blk = blockIdx.x, tid = threadIdx.x;

    if (blk < 256) {
        // ---------------- v path ----------------
        const int b = blk >> 6, t4 = (blk & 63) >> 2, eblk = blk & 3;
        const int px = tid;                  // 0..255
        const int n = t4 * 256 + px;

        __shared__ ushort vls[16 * 264];     // [row][px], stride 264 halves

        const float* xb = x + (size_t)(b * CC) * NN + n;
        float xc[CC];
#pragma unroll
        for (int c = 0; c < CC; ++c) xc[c] = xb[(size_t)c * NN];

#pragma unroll
        for (int r = 0; r < 16; ++r) {
            const int e = eblk * 16 + r;     // block-uniform row -> scalar loads
            const float* wr = Wv + e * CC;
            float a = bv[e];
#pragma unroll
            for (int c = 0; c < CC; ++c) a += wr[c] * xc[c];
            vls[r * 264 + px] = f2bf(a);
        }
        __syncthreads();

        // repack: chunk cidx -> (tt,s,quad,nn); 8 px-consecutive bf16 = b128
#pragma unroll
        for (int i = 0; i < 2; ++i) {
            const int cidx = tid + i * 256;
            const int nn = cidx & 15, quad = (cidx >> 4) & 3, s = (cidx >> 6) & 1, tt = cidx >> 7;
            const uint4 v4 = *(const uint4*)(vls + nn * 264 + tt * 64 + s * 32 + quad * 8);
            *(uint4*)(vsw + ((size_t)(b * 64 + t4 * 4 + tt) * 512 + (s * 4 + eblk) * 64 + quad * 16 + nn) * 8) = v4;
        }
        return;
    }

    // ---------------- qk path ----------------
    const int idx = (blk - 256) * 256 + tid;     // b*N + n
    const int b = idx >> 12, n = idx & (NN - 1);
    const int px = n & 63, t = n >> 6;

    const float* xb = x + (size_t)(b * CC) * NN + n;
    float xv[CC];
#pragma unroll
    for (int c = 0; c < CC; ++c) xv[c] = xb[(size_t)c * NN];

    float s[16];
#pragma unroll
    for (int r = 0; r < 16; ++r) {               // r compile-const -> scalar weights
        const float* wr = (r < 8) ? (Wq + r * CC) : (Wk + (r - 8) * CC);
        float a = (r < 8) ? bq[r] : bk[r - 8];
#pragma unroll
        for (int c = 0; c < CC; ++c) a += wr[c] * xv[c];
        s[r] = a;
    }

    ushort hq[16], hk[16];
#pragma unroll
    for (int d = 0; d < 8; ++d) { hq[d] = f2bf(s[d]); hk[d] = f2bf(s[8 + d]); }
    hq[8]  = hq[0];  hq[9]  = hq[1];
    hq[10] = f2bf(s[0] - bf2f(hq[0]));
    hq[11] = f2bf(s[1] - bf2f(hq[1]));
    const ushort hc = f2bf((float)px), hr = f2bf((float)t);
    hk[8] = hc; hk[9] = hr; hk[10] = hc; hk[11] = hr;
#pragma unroll
    for (int i = 12; i < 16; ++i) { hq[i] = 0; hk[i] = 0; }

    const uint4 z = {0u, 0u, 0u, 0u};
    uint4* dq = (uint4*)(qTp + (size_t)(b * NN + n) * 32);
    uint4* dk = (uint4*)(kTp + (size_t)(b * NN + n) * 32);
    dq[0] = ((const uint4*)hq)[0]; dq[1] = ((const uint4*)hq)[1]; dq[2] = z; dq[3] = z;
    dk[0] = ((const uint4*)hk)[0]; dk[1] = ((const uint4*)hk)[1]; dk[2] = z; dk[3] = z;

    // per-batch |k_d| max of bf16-rounded values; signed-int atomicMax
#pragma unroll
    for (int d = 0; d < 8; ++d) {
        float kv = fabsf(bf2f(hk[d]));
#pragma unroll
        for (int off = 1; off < 64; off <<= 1) kv = fmaxf(kv, __shfl_xor(kv, off, 64));
        if ((tid & 63) == 0) atomicMax(kmax + b * 8 + d, (int)__float_as_uint(kv));
    }
}

// ---------------------------------------------------------------------------
// Kernel 2: single-pass MFMA attention, register-resident P via ds_bpermute.
// 512 blocks; XCD-pair batch clustering: b = (blk&7)>>1 so each XCD's hot
// K/V set is one batch (3 MB < 4 MB L2). 512 threads = 8 waves, 8-way key
// split. V b128 loads hoisted to iteration top to overlap the QK->exp chain.
// ---------------------------------------------------------------------------
__global__ __launch_bounds__(512, 4) void attn_kernel(
    const ushort* __restrict__ qTp, const ushort* __restrict__ kTp,
    const ushort* __restrict__ vsw, const int* __restrict__ kmaxi,
    float* __restrict__ out)
{
    const int blk = blockIdx.x;
    const int b  = (blk & 7) >> 1;                         // XCD-pair batch
    const int nq = (((blk >> 3) << 1) | (blk & 1)) * 32;   // query tile 0..127
    const int tid = threadIdx.x, wv = tid >> 6, lane = tid & 63;
    const int nn = lane & 15, quad = lane >> 4;

    __shared__ float obuf[32 * 81];      // [q][81]: ch 0..63 = out, 64 = den
    for (int i = tid; i < 32 * 81; i += 512) obuf[i] = 0.f;

    // Q B-frags: lane holds channels quad*8..+8 of query (nq + qg*16 + nn)
    short8 qf[2];
    qf[0] = *(const short8*)(qTp + (size_t)(b * NN + nq + nn) * 32 + quad * 8);
    qf[1] = *(const short8*)(qTp + (size_t)(b * NN + nq + 16 + nn) * 32 + quad * 8);

    // ---- safe per-query softmax shift M~ (overestimate cancels in softmax) ----
    float Mq[2];
    {
        const int* kmax = kmaxi + b * 8;
#pragma unroll
        for (int qg = 0; qg < 2; ++qg) {
            float B1 = 0.f;   // valid on quad 0 (channels 0..7)
#pragma unroll
            for (int d = 0; d < 8; ++d)
                B1 += fabsf(bf2f((ushort)qf[qg][d])) * __uint_as_float((unsigned)kmax[d]);
            // valid on quad 1 (channels 8..11 = q0h,q1h,q0l,q1l)
            const float q0 = bf2f((ushort)qf[qg][0]) + bf2f((ushort)qf[qg][2]);
            const float q1 = bf2f((ushort)qf[qg][1]) + bf2f((ushort)qf[qg][3]);
            const float rel = fmaxf(q0 * 63.f, 0.f) + fmaxf(q1 * 63.f, 0.f);
            const float z  = (quad == 0) ? B1 : ((quad == 1) ? rel : 0.f);
            const float r1 = __shfl_xor(z, 16, 64);
            const float myB1  = (quad == 0) ? z : r1;
            const float myRel = (quad == 0) ? r1 : z;
            float f = myRel + fmaxf(myB1 - 20.f, 0.f) + 1.f;
            f = (quad < 2) ? f : 0.f;
            Mq[qg] = f + __shfl_xor(f, 32, 64);
        }
    }

    f32x4 acc[2][4];
#pragma unroll
    for (int qg = 0; qg < 2; ++qg)
#pragma unroll
        for (int g = 0; g < 4; ++g) acc[qg][g] = (f32x4){0.f, 0.f, 0.f, 0.f};
    float den[2] = {0.f, 0.f};

    const ushort* kb  = kTp + (size_t)b * NN * 32;
    const ushort* vb0 = vsw + (size_t)b * 64 * 512 * 8;
    const int addr0 = (((quad & 1) * 2 + 0) * 16 + nn) * 4;   // bpermute src (h=0)
    const int addr1 = (((quad & 1) * 2 + 1) * 16 + nn) * 4;   // bpermute src (h=1)
    const int hi = quad >> 1;                                  // kg select

    __syncthreads();   // obuf zeros visible before post-loop ds_add

    for (int it = 0; it < 8; ++it) {
        const int t = wv + it * 8;

        // independent loads first: K frags + ALL V frags (overlap QK/exp chain)
        short8 kf[4];
#pragma unroll
        for (int kg = 0; kg < 4; ++kg)
            kf[kg] = *(const short8*)(kb + (size_t)(t * 64 + kg * 16 + nn) * 32 + quad * 8);
        const ushort* vt0 = vb0 + (size_t)t * 512 * 8;
        short8 vf[2][4];
#pragma unroll
        for (int s = 0; s < 2; ++s)
#pragma unroll
            for (int g = 0; g < 4; ++g)
                vf[s][g] = *(const short8*)(vt0 + (size_t)((s * 4 + g) * 64 + lane) * 8);

        uint2 pk[2][4];
#pragma unroll
        for (int qg = 0; qg < 2; ++qg) {
#pragma unroll
            for (int kg = 0; kg < 4; ++kg) {
                f32x4 S = __builtin_amdgcn_mfma_f32_16x16x32_bf16(
                    kf[kg], qf[qg], (f32x4){0.f, 0.f, 0.f, 0.f}, 0, 0, 0);
                // lane = query nn ; regs = keys kg*16 + quad*4 .. +3
                const float w0 = __expf(S[0] - Mq[qg]);
                const float w1 = __expf(S[1] - Mq[qg]);
                const float w2 = __expf(S[2] - Mq[qg]);
                const float w3 = __expf(S[3] - Mq[qg]);
                den[qg] += (w0 + w1) + (w2 + w3);   // fp32 den (err <= 2e-3)
                union { __hip_bfloat162 h; unsigned u; } pa, pb;
                pa.h = __float22bfloat162_rn(make_float2(w0, w1));
                pb.h = __float22bfloat162_rn(make_float2(w2, w3));
                pk[qg][kg].x = pa.u; pk[qg][kg].y = pb.u;
            }
        }

        // PV: A-frags via bpermute exchange (C-layout -> A-layout permutation)
#pragma unroll
        for (int s = 0; s < 2; ++s) {
#pragma unroll
            for (int qg = 0; qg < 2; ++qg) {
                const uint2 pkA = pk[qg][2 * s], pkB = pk[qg][2 * s + 1];
                union { uint4 u; short8 h; } af;
                {
                    const int r0 = __builtin_amdgcn_ds_bpermute(addr0, (int)pkA.x);
                    const int r1 = __builtin_amdgcn_ds_bpermute(addr0, (int)pkB.x);
                    af.u.x = (unsigned)(hi ? r1 : r0);
                }
                {
                    const int r0 = __builtin_amdgcn_ds_bpermute(addr0, (int)pkA.y);
                    const int r1 = __builtin_amdgcn_ds_bpermute(addr0, (int)pkB.y);
                    af.u.y = (unsigned)(hi ? r1 : r0);
                }
                {
                    const int r0 = __builtin_amdgcn_ds_bpermute(addr1, (int)pkA.x);
                    const int r1 = __builtin_amdgcn_ds_bpermute(addr1, (int)pkB.x);
                    af.u.z = (unsigned)(hi ? r1 : r0);
                }
                {
                    const int r0 = __builtin_amdgcn_ds_bpermute(addr1, (int)pkA.y);
                    const int r1 = __builtin_amdgcn_ds_bpermute(addr1, (int)pkB.y);
                    af.u.w = (unsigned)(hi ? r1 : r0);
                }
#pragma unroll
                for (int g = 0; g < 4; ++g)
                    acc[qg][g] = __builtin_amdgcn_mfma_f32_16x16x32_bf16(af.h, vf[s][g], acc[qg][g], 0, 0, 0);
            }
        }
    }

    // ---- combine across the 8 key-split waves ----
#pragma unroll
    for (int qg = 0; qg < 2; ++qg) {
        float d = den[qg];
        d += __shfl_xor(d, 16, 64);
        d += __shfl_xor(d, 32, 64);
        if (lane < 16) atomicAdd(&obuf[(qg * 16 + lane) * 81 + 64], d);
    }
#pragma unroll
    for (int qg = 0; qg < 2; ++qg)
#pragma unroll
        for (int g = 0; g < 4; ++g)
#pragma unroll
            for (int r = 0; r < 4; ++r)
                atomicAdd(&obuf[(qg * 16 + quad * 4 + r) * 81 + g * 16 + nn], acc[qg][g][r]);
    __syncthreads();

    // epilogue: out[b][c][nq+q] ; lanes 0..31 = consecutive n (coalesced)
    {
        const int q = tid & 31, c0 = tid >> 5;
#pragma unroll
        for (int i = 0; i < 4; ++i) {
            const int c = c0 + i * 16;
            out[(size_t)(b * CC + c) * NN + nq + q] = obuf[q * 81 + c] / obuf[q * 81 + 64];
        }
    }
}

extern "C" void kernel_launch(void* const* d_in, const int* in_sizes, int n_in,
                              void* d_out, int out_size, void* d_ws, size_t ws_size,
                              hipStream_t stream) {
    const float* x  = (const float*)d_in[0];
    const float* Wq = (const float*)d_in[1];
    const float* bq = (const float*)d_in[2];
    const float* Wk = (const float*)d_in[3];
    const float* bk = (const float*)d_in[4];
    const float* Wv = (const float*)d_in[5];
    const float* bv = (const float*)d_in[6];
    float* out = (float*)d_out;

    ushort* ws  = (ushort*)d_ws;
    ushort* qTp = ws;                                     // B*N*32 halves
    ushort* kTp = qTp + (size_t)BB * NN * 32;             // B*N*32 halves
    ushort* vsw = kTp + (size_t)BB * NN * 32;             // B*64*512*8 halves
    int* kmax = (int*)(vsw + (size_t)BB * 64 * 512 * 8);  // B*8 (poison = neg int)

    qkv_kernel<<<320, 256, 0, stream>>>(x, Wq, bq, Wk, bk, Wv, bv, qTp, kTp, vsw, kmax);
    attn_kernel<<<BB * 128, 512, 0, stream>>>(qTp, kTp, vsw, kmax, out);
}